// Round 6
// baseline (93.414 us; speedup 1.0000x reference)
//
#include <hip/hip_runtime.h>
#include <hip/hip_fp16.h>
#include <math.h>

// DyDCNv2: B=8, C=256, O=256, H=W=64, 3x3 modulated deformable conv + GN16
#define BB 8
#define CC 256
#define OO 256
#define HH 64
#define WW 64
#define KK 9
#define HWSZ 4096
#define CKSZ 2304
#define NG 16
#define OPG 16
#define EPSV 1e-5f

typedef _Float16 f16;
typedef f16 f16x8 __attribute__((ext_vector_type(8)));
typedef float f32x4 __attribute__((ext_vector_type(4)));

#define XH_ELEMS ((size_t)BB*HWSZ*CC)    // 8,388,608 halves (16.8 MB)
#define WH_ELEMS ((size_t)OO*CKSZ)       //   589,824 halves (1.2 MB)
#define CV_ELEMS ((size_t)BB*OO*HWSZ)    // 8,388,608 halves (16.8 MB)
#define PSUM_FLOATS ((size_t)512*32)     // 64 KB

__device__ __forceinline__ void gload_lds16(const void* g, void* l) {
  __builtin_amdgcn_global_load_lds(
      (const __attribute__((address_space(1))) void*)g,
      (__attribute__((address_space(3))) void*)l, 16, 0, 0);
}

// ---- x[b][c][hw] fp32  ->  xh[b][hw][c] f16 (channel-contiguous for gathers)
__global__ __launch_bounds__(256) void x_transpose_k(
    const float* __restrict__ x, __half* __restrict__ xh)
{
  int blk = blockIdx.x;
  int b = blk >> 8; int rem = blk & 255;
  int c0 = (rem >> 6) * 64; int hw0 = (rem & 63) * 64;
  __shared__ float st[64][65];
  int t = threadIdx.x;
  #pragma unroll
  for (int i = 0; i < 16; ++i) {
    int idx = t + i*256; int c = idx >> 6, w = idx & 63;
    st[c][w] = x[((size_t)(b*CC + c0 + c))*HWSZ + hw0 + w];
  }
  __syncthreads();
  #pragma unroll
  for (int i = 0; i < 8; ++i) {
    int idx = t + i*256; int r = idx >> 5, cp = idx & 31;
    __half2 v = __floats2half2_rn(st[cp*2][r], st[cp*2+1][r]);
    *(__half2*)&xh[((size_t)(b*HWSZ) + hw0 + r)*CC + c0 + cp*2] = v;
  }
}

// ---- weight[o][c][k] fp32 -> wh[o][k*256+c] f16 (K reordered k-major)
__global__ __launch_bounds__(256) void w_reorder_k(
    const float* __restrict__ w, __half* __restrict__ wh)
{
  int i = blockIdx.x*256 + threadIdx.x;   // < 589824
  int o = i / CKSZ; int kp = i - o*CKSZ;
  int kk = kp >> 8, c = kp & 255;
  wh[i] = __float2half(w[o*CKSZ + c*KK + kk]);
}

// ---- fused deformable-conv GEMM, one block per (b, image row h) ----
// 256 thr = 4 waves; block tile 256o x 64p; wave tile 64o x 64p (wm = wid).
// 36 chunks (k 0..8 x c0 0..3), BK=64. Pipelined: A-frags->regs, async
// gload sW(next) + gather(next) issued before MFMA(cur); sV double-buffered.
// 2 blocks/CU (LDS 63KB). Epilogue: f16 conv out + per-block GN partials.
template<int F16OUT>
__global__ __launch_bounds__(256, 2) void dcn_mfma_k(
    const float* __restrict__ off, const float* __restrict__ msk,
    const __half* __restrict__ xh, const __half* __restrict__ wh,
    float* __restrict__ out32, __half* __restrict__ conv16,
    float* __restrict__ psum)
{
  __shared__ __half sWl[OO*64];        // 32768 B
  __shared__ __half sVl[2][64*64];     // 16384 B
  __shared__ uint   sTapO[KK][64][4];  //  9216 B
  __shared__ __half sTapW[KK][64][4];  //  4608 B
  __shared__ float  sRed[4][4][2];     //   128 B   (total ~63.1 KB)

  const int t = threadIdx.x;
  const int b = blockIdx.x & 7;        // XCD-pin: one batch per XCD
  const int h = blockIdx.x >> 3;       // image row 0..63

  const int lane = t & 63, wid = t >> 6;   // wid = wm (o-tile of 64)
  const int lr = lane & 15, lh = lane >> 4;
  const int gp = t >> 2, gq = t & 3;       // gather: p (0..63), octet pair {gq, gq+4}

  // ---- prologue: taps for ALL 9 kernel points of this row ----
  for (int s = t; s < KK*64; s += 256) {
    int k = s >> 6, p = s & 63;
    float dy = off[(((b*18) + 2*k    )*HH + h)*WW + p];
    float dx = off[(((b*18) + 2*k + 1)*HH + h)*WW + p];
    float m  = msk[(((b*KK) + k)*HH + h)*WW + p];
    float py = (float)(h + (k/3) - 1) + dy;
    float px = (float)(p + (k%3) - 1) + dx;
    float y0f = floorf(py), x0f = floorf(px);
    float wy = py - y0f, wx = px - x0f;
    int y0 = (int)y0f, x0 = (int)x0f;
    #pragma unroll
    for (int tap = 0; tap < 4; ++tap) {
      int yy = y0 + (tap >> 1), xx = x0 + (tap & 1);
      bool v = (yy >= 0) & (yy < HH) & (xx >= 0) & (xx < WW);
      float bw = ((tap >> 1) ? wy : 1.f - wy) * ((tap & 1) ? wx : 1.f - wx);
      float wgt = v ? bw * m : 0.f;
      int cy = min(max(yy, 0), HH-1), cx = min(max(xx, 0), WW-1);
      sTapO[k][p][tap] = (uint)((cy*WW + cx) * (CC*2));
      sTapW[k][p][tap] = __float2half(wgt);
    }
  }
  __syncthreads();   // taps ready

  f32x4 acc[4][4];
  #pragma unroll
  for (int mi = 0; mi < 4; ++mi)
    #pragma unroll
    for (int ni = 0; ni < 4; ++ni) acc[mi][ni] = (f32x4){0.f,0.f,0.f,0.f};

  const char* xbase = (const char*)xh + (size_t)b * (HWSZ*CC*2);

  // per-thread tap regs (current gather k)
  uint4 tO = *(const uint4*)&sTapO[0][gp][0];
  union { uint2 u; __half hh[4]; } tW;
  tW.u = *(const uint2*)&sTapW[0][gp][0];

  auto gload_sw = [&](int k, int c0) {
    #pragma unroll
    for (int i = 0; i < 8; ++i) {
      int idx = i*256 + t;
      int o = idx >> 3, s = idx & 7;
      const __half* g = wh + (size_t)o*CKSZ + k*256 + c0 + ((s ^ (o & 7)) << 3);
      char* ldsbase = (char*)sWl + (size_t)(i*256 + (t & ~63))*16;
      gload_lds16(g, ldsbase);
    }
  };

  // ---- prologue chunk 0: stage sW(0), gather+write sV[0] ----
  gload_sw(0, 0);
  {
    __half2 w0 = __half2half2(tW.hh[0]), w1 = __half2half2(tW.hh[1]);
    __half2 w2 = __half2half2(tW.hh[2]), w3 = __half2half2(tW.hh[3]);
    #pragma unroll
    for (int oi = 0; oi < 2; ++oi) {
      int oct = gq + oi*4;
      const char* cb = xbase + oct*16;
      uint4 r0 = *(const uint4*)(cb + tO.x);
      uint4 r1 = *(const uint4*)(cb + tO.y);
      uint4 r2 = *(const uint4*)(cb + tO.z);
      uint4 r3 = *(const uint4*)(cb + tO.w);
      const __half2* t0 = (const __half2*)&r0; const __half2* t1 = (const __half2*)&r1;
      const __half2* t2 = (const __half2*)&r2; const __half2* t3 = (const __half2*)&r3;
      __half2 o_[4];
      #pragma unroll
      for (int r = 0; r < 4; ++r)
        o_[r] = __hfma2(w0, t0[r], __hfma2(w1, t1[r],
                __hfma2(w2, t2[r], __hmul2(w3, t3[r]))));
      *(uint4*)&sVl[0][gp*64 + ((oct ^ (gp & 7)) << 3)] = *(uint4*)o_;
    }
  }

  int cur = 0;
  for (int cc = 0; cc < 36; ++cc) {
    const int k = cc >> 2;
    __syncthreads();   // [A] sW(cc) DMA drained; sV[cur] written

    // ---- A-frags -> regs (8 x ds_read_b128) ----
    f16x8 areg[2][4];
    #pragma unroll
    for (int ks = 0; ks < 2; ++ks)
      #pragma unroll
      for (int mi = 0; mi < 4; ++mi) {
        int r = wid*64 + mi*16 + lr;
        areg[ks][mi] = *(const f16x8*)&sWl[r*64 + (((ks*4 + lh) ^ (r & 7)) << 3)];
      }
    __syncthreads();   // [B] all waves done reading sWl

    // ---- prefetch chunk cc+1: async sW gload + gather global loads ----
    uint4 ga0, ga1, ga2, ga3, gb0, gb1, gb2, gb3;
    bool pf = (cc + 1 < 36);
    int kn = (cc+1) >> 2, c0n = ((cc+1) & 3) << 6;
    if (pf) {
      gload_sw(kn, c0n);
      if (kn != k) {
        tO = *(const uint4*)&sTapO[kn][gp][0];
        tW.u = *(const uint2*)&sTapW[kn][gp][0];
      }
      const char* cb = xbase + (size_t)(c0n*2) + gq*16;
      ga0 = *(const uint4*)(cb + tO.x);
      ga1 = *(const uint4*)(cb + tO.y);
      ga2 = *(const uint4*)(cb + tO.z);
      ga3 = *(const uint4*)(cb + tO.w);
      gb0 = *(const uint4*)(cb + tO.x + 64);
      gb1 = *(const uint4*)(cb + tO.y + 64);
      gb2 = *(const uint4*)(cb + tO.z + 64);
      gb3 = *(const uint4*)(cb + tO.w + 64);
    }

    // ---- MFMA(cc): B-frags from sV[cur], A from regs ----
    #pragma unroll
    for (int ks = 0; ks < 2; ++ks) {
      f16x8 brg[4];
      #pragma unroll
      for (int ni = 0; ni < 4; ++ni) {
        int r = ni*16 + lr;
        brg[ni] = *(const f16x8*)&sVl[cur][r*64 + (((ks*4 + lh) ^ (r & 7)) << 3)];
      }
      #pragma unroll
      for (int mi = 0; mi < 4; ++mi)
        #pragma unroll
        for (int ni = 0; ni < 4; ++ni)
          acc[mi][ni] = __builtin_amdgcn_mfma_f32_16x16x32_f16(
              areg[ks][mi], brg[ni], acc[mi][ni], 0, 0, 0);
    }

    // ---- combine + write sV[nxt] ----
    if (pf) {
      __half2 w0 = __half2half2(tW.hh[0]), w1 = __half2half2(tW.hh[1]);
      __half2 w2 = __half2half2(tW.hh[2]), w3 = __half2half2(tW.hh[3]);
      {
        const __half2* t0 = (const __half2*)&ga0; const __half2* t1 = (const __half2*)&ga1;
        const __half2* t2 = (const __half2*)&ga2; const __half2* t3 = (const __half2*)&ga3;
        __half2 o_[4];
        #pragma unroll
        for (int r = 0; r < 4; ++r)
          o_[r] = __hfma2(w0, t0[r], __hfma2(w1, t1[r],
                  __hfma2(w2, t2[r], __hmul2(w3, t3[r]))));
        *(uint4*)&sVl[cur ^ 1][gp*64 + ((gq ^ (gp & 7)) << 3)] = *(uint4*)o_;
      }
      {
        const __half2* t0 = (const __half2*)&gb0; const __half2* t1 = (const __half2*)&gb1;
        const __half2* t2 = (const __half2*)&gb2; const __half2* t3 = (const __half2*)&gb3;
        __half2 o_[4];
        #pragma unroll
        for (int r = 0; r < 4; ++r)
          o_[r] = __hfma2(w0, t0[r], __hfma2(w1, t1[r],
                  __hfma2(w2, t2[r], __hmul2(w3, t3[r]))));
        *(uint4*)&sVl[cur ^ 1][gp*64 + (((gq + 4) ^ (gp & 7)) << 3)] = *(uint4*)o_;
      }
      cur ^= 1;
    }
  }

  // ---- epilogue 1: conv output ----
  #pragma unroll
  for (int mi = 0; mi < 4; ++mi) {
    #pragma unroll
    for (int ni = 0; ni < 4; ++ni) {
      int ob = wid*64 + mi*16 + lh*4;
      int pp = ni*16 + lr;
      #pragma unroll
      for (int j = 0; j < 4; ++j) {
        size_t idx = ((size_t)(b*OO + ob + j))*HWSZ + h*WW + pp;
        if (F16OUT) conv16[idx] = __float2half(acc[mi][ni][j]);
        else        out32[idx] = acc[mi][ni][j];
      }
    }
  }

  // ---- epilogue 2: fused GN partials (group = wid*4+mi, one wave per group) ----
  if (F16OUT) {
    #pragma unroll
    for (int mi = 0; mi < 4; ++mi) {
      float s1 = 0.f, s2 = 0.f;
      #pragma unroll
      for (int ni = 0; ni < 4; ++ni)
        #pragma unroll
        for (int j = 0; j < 4; ++j) {
          float v = acc[mi][ni][j];
          s1 += v; s2 += v*v;
        }
      #pragma unroll
      for (int d = 32; d > 0; d >>= 1) {
        s1 += __shfl_xor(s1, d);
        s2 += __shfl_xor(s2, d);
      }
      if (lane == 0) { sRed[wid][mi][0] = s1; sRed[wid][mi][1] = s2; }
    }
    __syncthreads();
    if (t < 16) {   // group g = wid*4+mi -> sRed[g>>2][g&3]
      psum[(size_t)blockIdx.x*32 + t*2]     = sRed[t >> 2][t & 3][0];
      psum[(size_t)blockIdx.x*32 + t*2 + 1] = sRed[t >> 2][t & 3][1];
    }
  }
}

// ---- GN finalize: sum psum, normalize f16 conv -> f32 out ----
__global__ __launch_bounds__(256) void gn_norm2_k(
    const __half* __restrict__ conv16, const float* __restrict__ psum,
    const float* __restrict__ gamma, const float* __restrict__ beta,
    float* __restrict__ out)
{
  int bid = blockIdx.x;            // 4096
  int bo = bid >> 1;
  int b = bo >> 8, o = bo & 255;
  int g = o >> 4;
  float s1 = 0.f, s2 = 0.f;
  for (int hbl = 0; hbl < 64; ++hbl) {
    s1 += psum[(size_t)(hbl*8 + b)*32 + g*2];
    s2 += psum[(size_t)(hbl*8 + b)*32 + g*2 + 1];
  }
  const float invN = 1.f / (float)(OPG*HWSZ);
  float mean = s1 * invN;
  float var  = s2 * invN - mean*mean;
  float inv = rsqrtf(var + EPSV);
  float sc = gamma[o]*inv;
  float sh = beta[o] - mean*sc;

  size_t e0 = ((size_t)(b*OO + o))*HWSZ + (size_t)(bid & 1)*2048
            + (size_t)threadIdx.x*8;
  uint4 u = *(const uint4*)(conv16 + e0);
  const __half2* hh = (const __half2*)&u;
  float r[8];
  #pragma unroll
  for (int j = 0; j < 4; ++j) {
    float2 f = __half22float2(hh[j]);
    r[2*j] = f.x; r[2*j+1] = f.y;
  }
  *(float4*)&out[e0]     = make_float4(r[0]*sc+sh, r[1]*sc+sh, r[2]*sc+sh, r[3]*sc+sh);
  *(float4*)&out[e0 + 4] = make_float4(r[4]*sc+sh, r[5]*sc+sh, r[6]*sc+sh, r[7]*sc+sh);
}

// ---- fallback GN (f32 in-place) ----
__global__ __launch_bounds__(1024) void gn_stats_k(
    const float* __restrict__ out, float* __restrict__ stats)
{
  int bg = blockIdx.x;
  const float4* p = (const float4*)(out + (size_t)bg*OPG*HWSZ);
  const int n4 = OPG*HWSZ/4;
  float s1 = 0.f, s2 = 0.f;
  for (int i = threadIdx.x; i < n4; i += 1024) {
    float4 v = p[i];
    s1 += v.x + v.y + v.z + v.w;
    s2 += v.x*v.x + v.y*v.y + v.z*v.z + v.w*v.w;
  }
  #pragma unroll
  for (int o2 = 32; o2 > 0; o2 >>= 1) {
    s1 += __shfl_down(s1, o2);
    s2 += __shfl_down(s2, o2);
  }
  __shared__ float r1[16], r2[16];
  int wd = threadIdx.x >> 6, lane = threadIdx.x & 63;
  if (lane == 0) { r1[wd] = s1; r2[wd] = s2; }
  __syncthreads();
  if (threadIdx.x == 0) {
    float t1 = 0.f, t2 = 0.f;
    #pragma unroll
    for (int i = 0; i < 16; i++) { t1 += r1[i]; t2 += r2[i]; }
    const float invN = 1.f / (float)(OPG*HWSZ);
    float mean = t1 * invN;
    float var  = t2 * invN - mean*mean;
    stats[bg*2]   = mean;
    stats[bg*2+1] = var;
  }
}

__global__ __launch_bounds__(256) void gn_norm_k(
    float* __restrict__ out, const float* __restrict__ stats,
    const float* __restrict__ gamma, const float* __restrict__ beta)
{
  size_t i = (size_t)blockIdx.x*256 + threadIdx.x;
  const size_t n4 = (size_t)BB*OO*HWSZ/4;
  if (i >= n4) return;
  size_t base = i*4;
  int bo = (int)(base / HWSZ);
  int b = bo / OO, o = bo - b*OO;
  int g = o >> 4;
  float mean = stats[(b*NG+g)*2], var = stats[(b*NG+g)*2+1];
  float inv = rsqrtf(var + EPSV);
  float sc = gamma[o]*inv;
  float sh = beta[o] - mean*sc;
  float4 v = *(float4*)&out[base];
  v.x = v.x*sc + sh; v.y = v.y*sc + sh;
  v.z = v.z*sc + sh; v.w = v.w*sc + sh;
  *(float4*)&out[base] = v;
}

extern "C" void kernel_launch(void* const* d_in, const int* in_sizes, int n_in,
                              void* d_out, int out_size, void* d_ws, size_t ws_size,
                              hipStream_t stream) {
  const float* x      = (const float*)d_in[0];
  const float* offset = (const float*)d_in[1];
  const float* mask   = (const float*)d_in[2];
  const float* weight = (const float*)d_in[3];
  const float* gamma  = (const float*)d_in[4];
  const float* beta   = (const float*)d_in[5];
  float* out = (float*)d_out;

  __half* xh   = (__half*)d_ws;
  __half* wh   = xh + XH_ELEMS;
  __half* cv   = wh + WH_ELEMS;
  float* psum  = (float*)(cv + CV_ELEMS);

  const size_t need = (XH_ELEMS + WH_ELEMS + CV_ELEMS)*2 + PSUM_FLOATS*4 + 1024;

  x_transpose_k<<<BB*4*64, 256, 0, stream>>>(x, xh);
  w_reorder_k<<<(int)(WH_ELEMS/256), 256, 0, stream>>>(weight, wh);

  if (ws_size >= need) {
    dcn_mfma_k<1><<<512, 256, 0, stream>>>(offset, mask, xh, wh,
                                           (float*)nullptr, cv, psum);
    gn_norm2_k<<<4096, 256, 0, stream>>>(cv, psum, gamma, beta, out);
  } else {
    float* stats = (float*)(wh + WH_ELEMS);
    dcn_mfma_k<0><<<512, 256, 0, stream>>>(offset, mask, xh, wh,
                                           out, (__half*)nullptr, (float*)nullptr);
    gn_stats_k<<<BB*NG, 1024, 0, stream>>>(out, stats);
    gn_norm_k<<<(int)((size_t)BB*OO*HWSZ/4 + 255)/256, 256, 0, stream>>>(
        out, stats, gamma, beta);
  }
}

// Round 7
// 89.661 us; speedup vs baseline: 1.0419x; 1.0419x over previous
//
#include <hip/hip_runtime.h>
#include <hip/hip_fp16.h>
#include <math.h>

// DyDCNv2: B=8, C=256, O=256, H=W=64, 3x3 modulated deformable conv + GN16
#define BB 8
#define CC 256
#define OO 256
#define HH 64
#define WW 64
#define KK 9
#define HWSZ 4096
#define CKSZ 2304
#define NG 16
#define OPG 16
#define EPSV 1e-5f

typedef _Float16 f16;
typedef f16 f16x8 __attribute__((ext_vector_type(8)));
typedef float f32x4 __attribute__((ext_vector_type(4)));

#define XH_ELEMS ((size_t)BB*HWSZ*CC)    // 8,388,608 halves (16.8 MB)
#define WF_ELEMS ((size_t)OO*CKSZ)       //   589,824 halves (1.2 MB)
#define CV_ELEMS ((size_t)BB*OO*HWSZ)    // 8,388,608 halves (16.8 MB)
#define PSUM_FLOATS ((size_t)512*32)     // 64 KB

// ---- x[b][c][hw] fp32  ->  xh[b][hw][c] f16 (channel-contiguous for gathers)
__global__ __launch_bounds__(256) void x_transpose_k(
    const float* __restrict__ x, __half* __restrict__ xh)
{
  int blk = blockIdx.x;
  int b = blk >> 8; int rem = blk & 255;
  int c0 = (rem >> 6) * 64; int hw0 = (rem & 63) * 64;
  __shared__ float st[64][65];
  int t = threadIdx.x;
  #pragma unroll
  for (int i = 0; i < 16; ++i) {
    int idx = t + i*256; int c = idx >> 6, w = idx & 63;
    st[c][w] = x[((size_t)(b*CC + c0 + c))*HWSZ + hw0 + w];
  }
  __syncthreads();
  #pragma unroll
  for (int i = 0; i < 8; ++i) {
    int idx = t + i*256; int r = idx >> 5, cp = idx & 31;
    __half2 v = __floats2half2_rn(st[cp*2][r], st[cp*2+1][r]);
    *(__half2*)&xh[((size_t)(b*HWSZ) + hw0 + r)*CC + c0 + cp*2] = v;
  }
}

// ---- weight[o][c][3][3] fp32 -> fragment-ordered f16:
// wf[cc=k*4+c0i][wid][ks][mi][lane][e]; o=wid*64+mi*16+(lane&15),
// c=c0i*64+ks*32+(lane>>4)*8+e. Each (cc,wid,ks,mi): 64 lanes x 16B coalesced.
__global__ __launch_bounds__(256) void w_frag_k(
    const float* __restrict__ w, __half* __restrict__ wf)
{
  int i = blockIdx.x*256 + threadIdx.x;   // < 589824
  int e = i & 7, lane = (i >> 3) & 63, mi = (i >> 9) & 3;
  int ks = (i >> 11) & 1, wid = (i >> 12) & 3, cc = i >> 14;
  int k = cc >> 2, c0i = cc & 3;
  int o = wid*64 + mi*16 + (lane & 15);
  int c = c0i*64 + ks*32 + (lane >> 4)*8 + e;
  wf[i] = __float2half(w[(o*CC + c)*KK + k]);
}

// ---- fused deformable-conv GEMM, one block per (b, image row h) ----
// 256 thr = 4 waves; block tile 256o x 64p; wave tile 64o x 64p (wm = wid).
// A-frags read DIRECTLY from global wf (coalesced, L2-resident) -> no sW LDS,
// no DMA drain, ONE barrier per chunk. sV double-buffered, XOR-swizzled.
// Taps packed 4B. LDS ~25.7 KB -> 3 blocks/CU at <=170 VGPR.
template<int F16OUT>
__global__ __launch_bounds__(256, 3) void dcn_mfma_k(
    const float* __restrict__ off, const float* __restrict__ msk,
    const __half* __restrict__ xh, const __half* __restrict__ wf,
    float* __restrict__ out32, __half* __restrict__ conv16,
    float* __restrict__ psum)
{
  __shared__ __half sVl[2][64*64];     // 16384 B
  __shared__ uint   sTapP[KK][64][4];  //  9216 B (idx<<16 | f16-weight bits)
  __shared__ float  sRed[4][4][2];     //   128 B

  const int t = threadIdx.x;
  const int b = blockIdx.x & 7;        // XCD-pin: one batch per XCD
  const int h = blockIdx.x >> 3;       // image row 0..63

  const int lane = t & 63, wid = t >> 6;   // wid = o-tile of 64
  const int lr = lane & 15, lh = lane >> 4;
  const int gp = t >> 2, gq = t & 3;       // gather: p (0..63), octets {gq, gq+4}

  // ---- prologue: packed taps for all 9 kernel points of this row ----
  for (int s = t; s < KK*64; s += 256) {
    int k = s >> 6, p = s & 63;
    float dy = off[(((b*18) + 2*k    )*HH + h)*WW + p];
    float dx = off[(((b*18) + 2*k + 1)*HH + h)*WW + p];
    float m  = msk[(((b*KK) + k)*HH + h)*WW + p];
    float py = (float)(h + (k/3) - 1) + dy;
    float px = (float)(p + (k%3) - 1) + dx;
    float y0f = floorf(py), x0f = floorf(px);
    float wy = py - y0f, wx = px - x0f;
    int y0 = (int)y0f, x0 = (int)x0f;
    #pragma unroll
    for (int tap = 0; tap < 4; ++tap) {
      int yy = y0 + (tap >> 1), xx = x0 + (tap & 1);
      bool v = (yy >= 0) & (yy < HH) & (xx >= 0) & (xx < WW);
      float bw = ((tap >> 1) ? wy : 1.f - wy) * ((tap & 1) ? wx : 1.f - wx);
      float wgt = v ? bw * m : 0.f;
      int cy = min(max(yy, 0), HH-1), cx = min(max(xx, 0), WW-1);
      uint idx = (uint)(cy*WW + cx);
      sTapP[k][p][tap] = (idx << 16)
                       | (uint)__half_as_ushort(__float2half(wgt));
    }
  }
  __syncthreads();   // taps ready

  f32x4 acc[4][4];
  #pragma unroll
  for (int mi = 0; mi < 4; ++mi)
    #pragma unroll
    for (int ni = 0; ni < 4; ++ni) acc[mi][ni] = (f32x4){0.f,0.f,0.f,0.f};

  const char* xbase = (const char*)xh + (size_t)b * (HWSZ*CC*2);

  // gather-tap regs (current gather k)
  uint toff[4]; __half2 twv[4];
  #pragma unroll
  for (int i = 0; i < 4; ++i) {
    uint tp = sTapP[0][gp][i];
    toff[i] = (tp >> 16) << 9;           // byte offset = idx * 512
    twv[i]  = __half2half2(__ushort_as_half((unsigned short)(tp & 0xFFFFu)));
  }
  int tk = 0;

  auto combine_write = [&](uint4 r0, uint4 r1, uint4 r2, uint4 r3,
                           int oct, __half* dst) {
    const __half2* t0 = (const __half2*)&r0; const __half2* t1 = (const __half2*)&r1;
    const __half2* t2 = (const __half2*)&r2; const __half2* t3 = (const __half2*)&r3;
    __half2 o_[4];
    #pragma unroll
    for (int r = 0; r < 4; ++r)
      o_[r] = __hfma2(twv[0], t0[r], __hfma2(twv[1], t1[r],
              __hfma2(twv[2], t2[r], __hmul2(twv[3], t3[r]))));
    *(uint4*)&dst[gp*64 + ((oct ^ (gp & 7)) << 3)] = *(uint4*)o_;
  };

  // ---- prologue gather: chunk 0 -> sVl[0] ----
  {
    const char* cb = xbase + gq*16;
    uint4 a0 = *(const uint4*)(cb + toff[0]);
    uint4 a1 = *(const uint4*)(cb + toff[1]);
    uint4 a2 = *(const uint4*)(cb + toff[2]);
    uint4 a3 = *(const uint4*)(cb + toff[3]);
    uint4 b0 = *(const uint4*)(cb + toff[0] + 64);
    uint4 b1 = *(const uint4*)(cb + toff[1] + 64);
    uint4 b2 = *(const uint4*)(cb + toff[2] + 64);
    uint4 b3 = *(const uint4*)(cb + toff[3] + 64);
    combine_write(a0, a1, a2, a3, gq,     sVl[0]);
    combine_write(b0, b1, b2, b3, gq + 4, sVl[0]);
  }

  int cur = 0;
  for (int cc = 0; cc < 36; ++cc) {
    __syncthreads();   // sVl[cur] ready; prior reads of sVl[cur^1] done

    // ---- A-frags: 8 coalesced global loads (issued FIRST -> MFMA waits
    //      at vmcnt(8) while the 8 gathers below stay in flight) ----
    const __half* wfp = wf + (size_t)(cc*4 + wid)*4096 + lane*8;
    f16x8 areg[2][4];
    #pragma unroll
    for (int ks = 0; ks < 2; ++ks)
      #pragma unroll
      for (int mi = 0; mi < 4; ++mi)
        areg[ks][mi] = *(const f16x8*)(wfp + (ks*4 + mi)*512);

    // ---- gather issue for chunk cc+1 ----
    bool pf = (cc + 1 < 36);
    int kn = (cc+1) >> 2, c0n = ((cc+1) & 3) << 6;
    uint4 ga0, ga1, ga2, ga3, gb0, gb1, gb2, gb3;
    if (pf) {
      if (kn != tk) {
        #pragma unroll
        for (int i = 0; i < 4; ++i) {
          uint tp = sTapP[kn][gp][i];
          toff[i] = (tp >> 16) << 9;
          twv[i]  = __half2half2(__ushort_as_half((unsigned short)(tp & 0xFFFFu)));
        }
        tk = kn;
      }
      const char* cb = xbase + (size_t)(c0n*2) + gq*16;
      ga0 = *(const uint4*)(cb + toff[0]);
      ga1 = *(const uint4*)(cb + toff[1]);
      ga2 = *(const uint4*)(cb + toff[2]);
      ga3 = *(const uint4*)(cb + toff[3]);
      gb0 = *(const uint4*)(cb + toff[0] + 64);
      gb1 = *(const uint4*)(cb + toff[1] + 64);
      gb2 = *(const uint4*)(cb + toff[2] + 64);
      gb3 = *(const uint4*)(cb + toff[3] + 64);
    }

    // ---- MFMA(cc): B-frags from sVl[cur], A from regs ----
    #pragma unroll
    for (int ks = 0; ks < 2; ++ks) {
      f16x8 brg[4];
      #pragma unroll
      for (int ni = 0; ni < 4; ++ni) {
        int r = ni*16 + lr;
        brg[ni] = *(const f16x8*)&sVl[cur][r*64 + (((ks*4 + lh) ^ (r & 7)) << 3)];
      }
      #pragma unroll
      for (int mi = 0; mi < 4; ++mi)
        #pragma unroll
        for (int ni = 0; ni < 4; ++ni)
          acc[mi][ni] = __builtin_amdgcn_mfma_f32_16x16x32_f16(
              areg[ks][mi], brg[ni], acc[mi][ni], 0, 0, 0);
    }

    // ---- combine + write sVl[cur^1] ----
    if (pf) {
      combine_write(ga0, ga1, ga2, ga3, gq,     sVl[cur ^ 1]);
      combine_write(gb0, gb1, gb2, gb3, gq + 4, sVl[cur ^ 1]);
      cur ^= 1;
    }
  }

  // ---- epilogue 1: conv output ----
  #pragma unroll
  for (int mi = 0; mi < 4; ++mi) {
    #pragma unroll
    for (int ni = 0; ni < 4; ++ni) {
      int ob = wid*64 + mi*16 + lh*4;
      int pp = ni*16 + lr;
      #pragma unroll
      for (int j = 0; j < 4; ++j) {
        size_t idx = ((size_t)(b*OO + ob + j))*HWSZ + h*WW + pp;
        if (F16OUT) conv16[idx] = __float2half(acc[mi][ni][j]);
        else        out32[idx] = acc[mi][ni][j];
      }
    }
  }

  // ---- epilogue 2: fused GN partials (group = wid*4+mi, one wave per group) ----
  if (F16OUT) {
    #pragma unroll
    for (int mi = 0; mi < 4; ++mi) {
      float s1 = 0.f, s2 = 0.f;
      #pragma unroll
      for (int ni = 0; ni < 4; ++ni)
        #pragma unroll
        for (int j = 0; j < 4; ++j) {
          float v = acc[mi][ni][j];
          s1 += v; s2 += v*v;
        }
      #pragma unroll
      for (int d = 32; d > 0; d >>= 1) {
        s1 += __shfl_xor(s1, d);
        s2 += __shfl_xor(s2, d);
      }
      if (lane == 0) { sRed[wid][mi][0] = s1; sRed[wid][mi][1] = s2; }
    }
    __syncthreads();
    if (t < 16) {   // group g = wid*4+mi -> sRed[g>>2][g&3]
      psum[(size_t)blockIdx.x*32 + t*2]     = sRed[t >> 2][t & 3][0];
      psum[(size_t)blockIdx.x*32 + t*2 + 1] = sRed[t >> 2][t & 3][1];
    }
  }
}

// ---- GN finalize: sum psum, normalize f16 conv -> f32 out ----
__global__ __launch_bounds__(256) void gn_norm2_k(
    const __half* __restrict__ conv16, const float* __restrict__ psum,
    const float* __restrict__ gamma, const float* __restrict__ beta,
    float* __restrict__ out)
{
  int bid = blockIdx.x;            // 4096
  int bo = bid >> 1;
  int b = bo >> 8, o = bo & 255;
  int g = o >> 4;
  float s1 = 0.f, s2 = 0.f;
  for (int hbl = 0; hbl < 64; ++hbl) {
    s1 += psum[(size_t)(hbl*8 + b)*32 + g*2];
    s2 += psum[(size_t)(hbl*8 + b)*32 + g*2 + 1];
  }
  const float invN = 1.f / (float)(OPG*HWSZ);
  float mean = s1 * invN;
  float var  = s2 * invN - mean*mean;
  float inv = rsqrtf(var + EPSV);
  float sc = gamma[o]*inv;
  float sh = beta[o] - mean*sc;

  size_t e0 = ((size_t)(b*OO + o))*HWSZ + (size_t)(bid & 1)*2048
            + (size_t)threadIdx.x*8;
  uint4 u = *(const uint4*)(conv16 + e0);
  const __half2* hh = (const __half2*)&u;
  float r[8];
  #pragma unroll
  for (int j = 0; j < 4; ++j) {
    float2 f = __half22float2(hh[j]);
    r[2*j] = f.x; r[2*j+1] = f.y;
  }
  *(float4*)&out[e0]     = make_float4(r[0]*sc+sh, r[1]*sc+sh, r[2]*sc+sh, r[3]*sc+sh);
  *(float4*)&out[e0 + 4] = make_float4(r[4]*sc+sh, r[5]*sc+sh, r[6]*sc+sh, r[7]*sc+sh);
}

// ---- fallback GN (f32 in-place) ----
__global__ __launch_bounds__(1024) void gn_stats_k(
    const float* __restrict__ out, float* __restrict__ stats)
{
  int bg = blockIdx.x;
  const float4* p = (const float4*)(out + (size_t)bg*OPG*HWSZ);
  const int n4 = OPG*HWSZ/4;
  float s1 = 0.f, s2 = 0.f;
  for (int i = threadIdx.x; i < n4; i += 1024) {
    float4 v = p[i];
    s1 += v.x + v.y + v.z + v.w;
    s2 += v.x*v.x + v.y*v.y + v.z*v.z + v.w*v.w;
  }
  #pragma unroll
  for (int o2 = 32; o2 > 0; o2 >>= 1) {
    s1 += __shfl_down(s1, o2);
    s2 += __shfl_down(s2, o2);
  }
  __shared__ float r1[16], r2[16];
  int wd = threadIdx.x >> 6, lane = threadIdx.x & 63;
  if (lane == 0) { r1[wd] = s1; r2[wd] = s2; }
  __syncthreads();
  if (threadIdx.x == 0) {
    float t1 = 0.f, t2 = 0.f;
    #pragma unroll
    for (int i = 0; i < 16; i++) { t1 += r1[i]; t2 += r2[i]; }
    const float invN = 1.f / (float)(OPG*HWSZ);
    float mean = t1 * invN;
    float var  = t2 * invN - mean*mean;
    stats[bg*2]   = mean;
    stats[bg*2+1] = var;
  }
}

__global__ __launch_bounds__(256) void gn_norm_k(
    float* __restrict__ out, const float* __restrict__ stats,
    const float* __restrict__ gamma, const float* __restrict__ beta)
{
  size_t i = (size_t)blockIdx.x*256 + threadIdx.x;
  const size_t n4 = (size_t)BB*OO*HWSZ/4;
  if (i >= n4) return;
  size_t base = i*4;
  int bo = (int)(base / HWSZ);
  int b = bo / OO, o = bo - b*OO;
  int g = o >> 4;
  float mean = stats[(b*NG+g)*2], var = stats[(b*NG+g)*2+1];
  float inv = rsqrtf(var + EPSV);
  float sc = gamma[o]*inv;
  float sh = beta[o] - mean*sc;
  float4 v = *(float4*)&out[base];
  v.x = v.x*sc + sh; v.y = v.y*sc + sh;
  v.z = v.z*sc + sh; v.w = v.w*sc + sh;
  *(float4*)&out[base] = v;
}

extern "C" void kernel_launch(void* const* d_in, const int* in_sizes, int n_in,
                              void* d_out, int out_size, void* d_ws, size_t ws_size,
                              hipStream_t stream) {
  const float* x      = (const float*)d_in[0];
  const float* offset = (const float*)d_in[1];
  const float* mask   = (const float*)d_in[2];
  const float* weight = (const float*)d_in[3];
  const float* gamma  = (const float*)d_in[4];
  const float* beta   = (const float*)d_in[5];
  float* out = (float*)d_out;

  __half* xh   = (__half*)d_ws;
  __half* wf   = xh + XH_ELEMS;
  __half* cv   = wf + WF_ELEMS;
  float* psum  = (float*)(cv + CV_ELEMS);

  const size_t need = (XH_ELEMS + WF_ELEMS + CV_ELEMS)*2 + PSUM_FLOATS*4 + 1024;

  x_transpose_k<<<BB*4*64, 256, 0, stream>>>(x, xh);
  w_frag_k<<<(int)(WF_ELEMS/256), 256, 0, stream>>>(weight, wf);

  if (ws_size >= need) {
    dcn_mfma_k<1><<<512, 256, 0, stream>>>(offset, mask, xh, wf,
                                           (float*)nullptr, cv, psum);
    gn_norm2_k<<<4096, 256, 0, stream>>>(cv, psum, gamma, beta, out);
  } else {
    float* stats = (float*)(wf + WF_ELEMS);
    dcn_mfma_k<0><<<512, 256, 0, stream>>>(offset, mask, xh, wf,
                                           out, (__half*)nullptr, (float*)nullptr);
    gn_stats_k<<<BB*NG, 1024, 0, stream>>>(out, stats);
    gn_norm_k<<<(int)((size_t)BB*OO*HWSZ/4 + 255)/256, 256, 0, stream>>>(
        out, stats, gamma, beta);
  }
}